// Round 11
// baseline (782.371 us; speedup 1.0000x reference)
//
#include <hip/hip_runtime.h>
#include <hip/hip_cooperative_groups.h>
#include <hip/hip_fp16.h>
#include <math.h>

namespace cg = cooperative_groups;

#define N_NODES   50000
#define N_EDGES   800000
#define IN_DIM    128
#define HID       64
#define OUT_DIM   128
#define N_GRAPHS  256
#define MAX_DEG   64      // ELL row stride; P(deg>64) ~ 1e-19
#define AGG_NPB   32      // nodes per agg work-block (4 waves x 8 octets)
#define NB_MFMA   ((N_NODES + 63) / 64)              // 782
#define NB_AGG    ((N_NODES + AGG_NPB - 1) / AGG_NPB) // 1563

typedef _Float16 half8 __attribute__((ext_vector_type(8)));
typedef float floatx4 __attribute__((ext_vector_type(4)));
typedef unsigned int uintx4 __attribute__((ext_vector_type(4)));

struct Params {
    const float* x; const int* esrc; const int* edst; const int* batch;
    const float* W1; const float* b1; const float* W2; const float* b2;
    const float* W3; const float* b3; float* out;
    int* deg; float* dinv; int* col;
    __half* t; __half* p; __half* Wt1; __half* Wt2;
};

__device__ __forceinline__ void add8(float* acc, uintx4 v) {
    const __half2* h = (const __half2*)&v;
#pragma unroll
    for (int j = 0; j < 4; j++) {
        acc[2 * j]     += __low2float(h[j]);
        acc[2 * j + 1] += __high2float(h[j]);
    }
}

// ---- stage: MFMA GEMM layer 1, C = (dinv ⊙ x_fp32) @ W1 (cvt fused) ----
__device__ void mfma1_stage(const float* __restrict__ A, const float* __restrict__ dinv,
                            const __half* __restrict__ Bp, __half* __restrict__ C) {
    constexpr int S = IN_DIM / 32;
    int tid = threadIdx.x;
    int wv = tid >> 6, lane = tid & 63, quad = lane >> 4, l15 = lane & 15;
    half8 bf[S][4];                      // hoisted across tiles
#pragma unroll
    for (int s = 0; s < S; s++)
#pragma unroll
        for (int j = 0; j < 4; j++)
            bf[s][j] = *(const half8*)(Bp + ((size_t)((4 * s + quad) * 64 + 16 * j + l15)) * 8);
    for (int tile = blockIdx.x; tile < NB_MFMA; tile += gridDim.x) {
        int row0 = tile * 64 + wv * 16;
        if (row0 < N_NODES) {
            floatx4 acc[4];
#pragma unroll
            for (int j = 0; j < 4; j++) acc[j] = 0.f;
            int arow = row0 + l15;
            float dv = dinv[arow];
#pragma unroll
            for (int s = 0; s < S; s++) {
                floatx4 xa = __builtin_nontemporal_load((const floatx4*)(A + (size_t)arow * IN_DIM + 32 * s + quad * 8));
                floatx4 xb = __builtin_nontemporal_load((const floatx4*)(A + (size_t)arow * IN_DIM + 32 * s + quad * 8 + 4));
                half8 af;
                af[0] = (_Float16)(xa[0] * dv); af[1] = (_Float16)(xa[1] * dv);
                af[2] = (_Float16)(xa[2] * dv); af[3] = (_Float16)(xa[3] * dv);
                af[4] = (_Float16)(xb[0] * dv); af[5] = (_Float16)(xb[1] * dv);
                af[6] = (_Float16)(xb[2] * dv); af[7] = (_Float16)(xb[3] * dv);
#pragma unroll
                for (int j = 0; j < 4; j++)
                    acc[j] = __builtin_amdgcn_mfma_f32_16x16x32_f16(af, bf[s][j], acc[j], 0, 0, 0);
            }
#pragma unroll
            for (int j = 0; j < 4; j++)
#pragma unroll
                for (int r = 0; r < 4; r++)
                    C[(size_t)(row0 + quad * 4 + r) * 64 + 16 * j + l15] = __float2half(acc[j][r]);
        }
    }
}

// ---- stage: MFMA GEMM layer 2 (fp16 A) ----
__device__ void mfma2_stage(const __half* __restrict__ A, const __half* __restrict__ Bp,
                            __half* __restrict__ C) {
    constexpr int S = HID / 32;
    int tid = threadIdx.x;
    int wv = tid >> 6, lane = tid & 63, quad = lane >> 4, l15 = lane & 15;
    half8 bf[S][4];
#pragma unroll
    for (int s = 0; s < S; s++)
#pragma unroll
        for (int j = 0; j < 4; j++)
            bf[s][j] = *(const half8*)(Bp + ((size_t)((4 * s + quad) * 64 + 16 * j + l15)) * 8);
    for (int tile = blockIdx.x; tile < NB_MFMA; tile += gridDim.x) {
        int row0 = tile * 64 + wv * 16;
        if (row0 < N_NODES) {
            floatx4 acc[4];
#pragma unroll
            for (int j = 0; j < 4; j++) acc[j] = 0.f;
            int arow = row0 + l15;
#pragma unroll
            for (int s = 0; s < S; s++) {
                half8 af = *(const half8*)(A + (size_t)arow * HID + 32 * s + quad * 8);
#pragma unroll
                for (int j = 0; j < 4; j++)
                    acc[j] = __builtin_amdgcn_mfma_f32_16x16x32_f16(af, bf[s][j], acc[j], 0, 0, 0);
            }
#pragma unroll
            for (int j = 0; j < 4; j++)
#pragma unroll
                for (int r = 0; r < 4; r++)
                    C[(size_t)(row0 + quad * 4 + r) * 64 + 16 * j + l15] = __float2half(acc[j][r]);
        }
    }
}

// ---- stage: aggregation (LDS-staged ELL, 8 nodes/wave, 8-deep MLP) ----
__device__ void agg_stage(const __half* __restrict__ T, const int* __restrict__ col,
                          const int* __restrict__ deg, const float* __restrict__ dinv,
                          const float* __restrict__ bias, __half* __restrict__ OUT,
                          int mode, int (*cols)[MAX_DEG + 1]) {
    int tid = threadIdx.x;
    int lane = tid & 63, wv = tid >> 6;
    int q = lane >> 3, t = lane & 7;
    int local = wv * 8 + q;
    for (int w = blockIdx.x; w < NB_AGG; w += gridDim.x) {
        __syncthreads();                         // LDS reuse guard
        int base = w * AGG_NPB;
        for (int idx = tid; idx < AGG_NPB * MAX_DEG; idx += 256) {
            int r = idx >> 6, j = idx & 63, g = base + r;
            if (g < N_NODES) cols[r][j] = __builtin_nontemporal_load(&col[g * MAX_DEG + j]);
        }
        __syncthreads();
        int d = base + local;
        if (d < N_NODES) {
            int dg = deg[d]; if (dg > MAX_DEG) dg = MAX_DEG;
            float acc[8];
#pragma unroll
            for (int j = 0; j < 8; j++) acc[j] = 0.f;
            add8(acc, *(const uintx4*)(T + (size_t)d * HID + t * 8));   // self
            const int* cl = cols[local];
            int i = 0;
            for (; i + 8 <= dg; i += 8) {
                uintx4 v[8];
#pragma unroll
                for (int u = 0; u < 8; u++)
                    v[u] = *(const uintx4*)(T + (size_t)cl[i + u] * HID + t * 8);
#pragma unroll
                for (int u = 0; u < 8; u++) add8(acc, v[u]);
            }
            for (; i + 2 <= dg; i += 2) {
                uintx4 v0 = *(const uintx4*)(T + (size_t)cl[i] * HID + t * 8);
                uintx4 v1 = *(const uintx4*)(T + (size_t)cl[i + 1] * HID + t * 8);
                add8(acc, v0); add8(acc, v1);
            }
            if (i < dg)
                add8(acc, *(const uintx4*)(T + (size_t)cl[i] * HID + t * 8));

            float dv = dinv[d];
            float o[8];
#pragma unroll
            for (int j = 0; j < 8; j++) o[j] = acc[j] * dv;
            if (mode == 0) {
#pragma unroll
                for (int j = 0; j < 8; j++) {
                    float v = o[j] + bias[t * 8 + j];
                    float u2 = 0.7978845608028654f * (v + 0.044715f * v * v * v);
                    o[j] = 0.5f * v * (1.0f + tanhf(u2)) * dv;   // pre-scale for next layer
                }
            }
            __half2 hh[4];
#pragma unroll
            for (int j = 0; j < 4; j++) hh[j] = __floats2half2_rn(o[2 * j], o[2 * j + 1]);
            uintx4 st = *(uintx4*)hh;
            __builtin_nontemporal_store(st, (uintx4*)(OUT + (size_t)d * HID + t * 8));
        }
    }
}

// ---- stage: segmented mean-pool + final 64->128 GEMM (batch sorted) ----
__device__ void pool_stage(const __half* __restrict__ A, const int* __restrict__ batch,
                           const float* __restrict__ W3, const float* __restrict__ b3,
                           float* __restrict__ out, float (*part)[HID], float* pooled) {
    int tid = threadIdx.x;
    int lane = tid & 63, wave = tid >> 6;
    for (int g = blockIdx.x; g < N_GRAPHS; g += gridDim.x) {
        __syncthreads();
        int lo = 0, hi = N_NODES;
        while (lo < hi) { int m = (lo + hi) >> 1; if (batch[m] < g) lo = m + 1; else hi = m; }
        int lo2 = lo, hi2 = N_NODES;
        while (lo2 < hi2) { int m = (lo2 + hi2) >> 1; if (batch[m] < g + 1) lo2 = m + 1; else hi2 = m; }
        int start = lo, end = lo2;
        float acc = 0.f;
        for (int n = start + wave; n < end; n += 4)
            acc += __half2float(A[(size_t)n * HID + lane]);
        part[wave][lane] = acc;
        __syncthreads();
        if (tid < HID)
            pooled[tid] = part[0][tid] + part[1][tid] + part[2][tid] + part[3][tid];
        __syncthreads();
        if (tid < OUT_DIM) {
            float cntf = (float)(end - start);
            float inv = 1.0f / fmaxf(cntf, 1.0f);
            float s = 0.f;
#pragma unroll
            for (int k = 0; k < HID; k++) s += pooled[k] * W3[k * OUT_DIM + tid];
            out[g * OUT_DIM + tid] = (s + cntf * b3[tid]) * inv;
        }
    }
}

// ---------------- the mega-kernel ----------------

__global__ __launch_bounds__(256, 4) void mega(Params P) {
    __shared__ int cols[AGG_NPB][MAX_DEG + 1];
    __shared__ float part[4][HID];
    __shared__ float pooled[HID];
    cg::grid_group grid = cg::this_grid();
    int tid  = threadIdx.x;
    int gtid = blockIdx.x * 256 + tid;
    int gsz  = gridDim.x * 256;

    // stage 0: zero deg
    for (int i = gtid; i < N_NODES; i += gsz) P.deg[i] = 0;
    grid.sync();

    // stage 1: XCD-partitioned ELL build (blockIdx%8 -> partition)
    {
        int prt = blockIdx.x & 7, chunk = blockIdx.x >> 3;
        int chunks = gridDim.x >> 3;
        int epb = (N_EDGES + chunks - 1) / chunks;
        int base = chunk * epb;
        int lim = base + epb; if (lim > N_EDGES) lim = N_EDGES;
        int lo = prt * (N_NODES / 8), hi = lo + (N_NODES / 8);
        for (int e = base + tid; e < lim; e += 256) {
            int d = P.edst[e];
            if (d >= lo && d < hi) {
                int s = P.esrc[e];
                int pos = atomicAdd(&P.deg[d], 1);
                if (pos < MAX_DEG) P.col[d * MAX_DEG + pos] = s;
            }
        }
    }
    grid.sync();

    // stage 2: dinv + weight packs
    for (int n = gtid; n < N_NODES; n += gsz)
        P.dinv[n] = rsqrtf((float)(P.deg[n] + 1));          // +1 self-loop
    if (gtid < (IN_DIM / 8) * 64) {
        int g2 = gtid >> 6, n = gtid & 63;
#pragma unroll
        for (int i = 0; i < 8; i++)
            P.Wt1[gtid * 8 + i] = __float2half(P.W1[(8 * g2 + i) * 64 + n]);
    }
    if (gtid < (HID / 8) * 64) {
        int g2 = gtid >> 6, n = gtid & 63;
#pragma unroll
        for (int i = 0; i < 8; i++)
            P.Wt2[gtid * 8 + i] = __float2half(P.W2[(8 * g2 + i) * 64 + n]);
    }
    grid.sync();

    // layer 1
    mfma1_stage(P.x, P.dinv, P.Wt1, P.t);
    grid.sync();
    agg_stage(P.t, P.col, P.deg, P.dinv, P.b1, P.p, 0, cols);
    grid.sync();
    // layer 2
    mfma2_stage(P.p, P.Wt2, P.t);
    grid.sync();
    agg_stage(P.t, P.col, P.deg, P.dinv, P.b2, P.p, 0, cols);
    grid.sync();
    // layer 3 aggregate (pre-GEMM, width 64)
    agg_stage(P.p, P.col, P.deg, P.dinv, P.b3, P.t, 1, cols);
    grid.sync();
    // pool + final GEMM
    pool_stage(P.t, P.batch, P.W3, P.b3, P.out, part, pooled);
}

// ---------------- launch ----------------

extern "C" void kernel_launch(void* const* d_in, const int* in_sizes, int n_in,
                              void* d_out, int out_size, void* d_ws, size_t ws_size,
                              hipStream_t stream) {
    Params P;
    P.x     = (const float*)d_in[0];
    const int* ei = (const int*)d_in[1];
    P.esrc  = ei;
    P.edst  = ei + N_EDGES;
    P.batch = (const int*)d_in[2];
    P.W1 = (const float*)d_in[4]; P.b1 = (const float*)d_in[5];
    P.W2 = (const float*)d_in[6]; P.b2 = (const float*)d_in[7];
    P.W3 = (const float*)d_in[8]; P.b3 = (const float*)d_in[9];
    P.out = (float*)d_out;

    P.deg  = (int*)d_ws;                                   // 50000
    P.dinv = (float*)(P.deg + N_NODES);                    // 50000
    P.col  = (int*)(P.dinv + N_NODES);                     // 3.2M ints
    P.t    = (__half*)(P.col + (size_t)N_NODES * MAX_DEG); // 3.2M halves
    P.p    = P.t + (size_t)N_NODES * HID;                  // 3.2M halves
    P.Wt1  = P.p + (size_t)N_NODES * HID;                  // 8192 halves
    P.Wt2  = P.Wt1 + IN_DIM * HID;                         // 4096 halves

    int nb = 0;
    (void)hipOccupancyMaxActiveBlocksPerMultiprocessor(&nb, mega, 256, 0);
    if (nb < 1) nb = 1;
    if (nb > 4) nb = 4;
    int grid = nb * 256;                                   // multiple of 8 (build partitioning)

    void* args[] = { (void*)&P };
    (void)hipLaunchCooperativeKernel(mega, dim3(grid), dim3(256), args, 0, stream);
}

// Round 12
// 245.792 us; speedup vs baseline: 3.1831x; 3.1831x over previous
//
#include <hip/hip_runtime.h>
#include <hip/hip_fp16.h>
#include <math.h>

#define N_NODES   50000
#define N_EDGES   800000
#define IN_DIM    128
#define HID       64
#define OUT_DIM   128
#define N_GRAPHS  256
#define MAX_DEG   64      // ELL row stride; P(deg>64) ~ 1e-19
#define PARTS     8       // XCD count; blockIdx%8 -> XCD round-robin heuristic
#define PSIZE     (N_NODES / PARTS)
#define EPB       4096    // edges per build chunk
#define AGG_NPB   16      // nodes per agg block (2 wave-pairs x 8 nodes); 50000/16 = 3125 exact

typedef _Float16 half8 __attribute__((ext_vector_type(8)));
typedef float floatx4 __attribute__((ext_vector_type(4)));
typedef unsigned int uintx4 __attribute__((ext_vector_type(4)));

// ---------------- preprocessing ----------------

// XCD-partitioned single-cursor ELL build (best-measured R6 form)
__global__ __launch_bounds__(256) void k_build(const int* __restrict__ src,
                                               const int* __restrict__ dst,
                                               int* __restrict__ deg, int* __restrict__ col) {
    int p     = blockIdx.x & (PARTS - 1);
    int chunk = blockIdx.x >> 3;
    int base  = chunk * EPB;
    int lo = p * PSIZE, hi = lo + PSIZE;
#pragma unroll
    for (int j = 0; j < EPB / 256; j++) {
        int e = base + j * 256 + threadIdx.x;
        if (e < N_EDGES) {
            int d = dst[e];
            if (d >= lo && d < hi) {
                int pos = atomicAdd(&deg[d], 1);
                if (pos < MAX_DEG) col[d * MAX_DEG + pos] = src[e];
            }
        }
    }
}

// merged: dinv (blocks 0..195) + pack W1 (196..199) + pack W2 (200..201)
__global__ __launch_bounds__(256) void k_prep(const int* __restrict__ deg,
                                              float* __restrict__ dinv,
                                              const float* __restrict__ W1, __half* __restrict__ Wt1,
                                              const float* __restrict__ W2, __half* __restrict__ Wt2) {
    int blk = blockIdx.x;
    if (blk < 196) {
        int n = blk * 256 + threadIdx.x;
        if (n < N_NODES) dinv[n] = rsqrtf((float)(deg[n] + 1));  // +1 self-loop
    } else if (blk < 200) {
        int idx = (blk - 196) * 256 + threadIdx.x;   // (128/8)*64 = 1024
        int g = idx >> 6, n = idx & 63;
#pragma unroll
        for (int i = 0; i < 8; i++)
            Wt1[idx * 8 + i] = __float2half(W1[(8 * g + i) * 64 + n]);
    } else {
        int idx = (blk - 200) * 256 + threadIdx.x;   // (64/8)*64 = 512
        if (idx < 512) {
            int g = idx >> 6, n = idx & 63;
#pragma unroll
            for (int i = 0; i < 8; i++)
                Wt2[idx * 8 + i] = __float2half(W2[(8 * g + i) * 64 + n]);
        }
    }
}

// ---------------- MFMA GEMM layer 1: C = (dinv ⊙ x_fp32) @ W1, cvt fused ----------------

__global__ __launch_bounds__(256) void k_mfma1(const float* __restrict__ A,
                                               const float* __restrict__ dinv,
                                               const __half* __restrict__ Bp,
                                               __half* __restrict__ C) {
    constexpr int K = IN_DIM, S = K / 32;
    int wv   = threadIdx.x >> 6;
    int lane = threadIdx.x & 63;
    int quad = lane >> 4, l15 = lane & 15;
    int row0 = blockIdx.x * 64 + wv * 16;
    if (row0 >= N_NODES) return;   // 50000 % 16 == 0

    half8 bf[S][4];
#pragma unroll
    for (int s = 0; s < S; s++)
#pragma unroll
        for (int j = 0; j < 4; j++)
            bf[s][j] = *(const half8*)(Bp + ((size_t)((4 * s + quad) * 64 + 16 * j + l15)) * 8);

    floatx4 acc[4];
#pragma unroll
    for (int j = 0; j < 4; j++) acc[j] = 0.f;

    int arow = row0 + l15;
    float dv = dinv[arow];
#pragma unroll
    for (int s = 0; s < S; s++) {
        floatx4 xa = __builtin_nontemporal_load((const floatx4*)(A + (size_t)arow * K + 32 * s + quad * 8));
        floatx4 xb = __builtin_nontemporal_load((const floatx4*)(A + (size_t)arow * K + 32 * s + quad * 8 + 4));
        half8 af;
        af[0] = (_Float16)(xa[0] * dv); af[1] = (_Float16)(xa[1] * dv);
        af[2] = (_Float16)(xa[2] * dv); af[3] = (_Float16)(xa[3] * dv);
        af[4] = (_Float16)(xb[0] * dv); af[5] = (_Float16)(xb[1] * dv);
        af[6] = (_Float16)(xb[2] * dv); af[7] = (_Float16)(xb[3] * dv);
#pragma unroll
        for (int j = 0; j < 4; j++)
            acc[j] = __builtin_amdgcn_mfma_f32_16x16x32_f16(af, bf[s][j], acc[j], 0, 0, 0);
    }
#pragma unroll
    for (int j = 0; j < 4; j++)
#pragma unroll
        for (int r = 0; r < 4; r++)
            C[(size_t)(row0 + quad * 4 + r) * 64 + 16 * j + l15] = __float2half(acc[j][r]);
}

// ---------------- MFMA GEMM layer 2: fp16 A ----------------

__global__ __launch_bounds__(256) void k_mfma2(const __half* __restrict__ A,
                                               const __half* __restrict__ Bp,
                                               __half* __restrict__ C) {
    constexpr int S = HID / 32;
    int wv   = threadIdx.x >> 6;
    int lane = threadIdx.x & 63;
    int quad = lane >> 4, l15 = lane & 15;
    int row0 = blockIdx.x * 64 + wv * 16;
    if (row0 >= N_NODES) return;

    half8 bf[S][4];
#pragma unroll
    for (int s = 0; s < S; s++)
#pragma unroll
        for (int j = 0; j < 4; j++)
            bf[s][j] = *(const half8*)(Bp + ((size_t)((4 * s + quad) * 64 + 16 * j + l15)) * 8);

    floatx4 acc[4];
#pragma unroll
    for (int j = 0; j < 4; j++) acc[j] = 0.f;

    int arow = row0 + l15;
#pragma unroll
    for (int s = 0; s < S; s++) {
        half8 af = *(const half8*)(A + (size_t)arow * HID + 32 * s + quad * 8);
#pragma unroll
        for (int j = 0; j < 4; j++)
            acc[j] = __builtin_amdgcn_mfma_f32_16x16x32_f16(af, bf[s][j], acc[j], 0, 0, 0);
    }
#pragma unroll
    for (int j = 0; j < 4; j++)
#pragma unroll
        for (int r = 0; r < 4; r++)
            C[(size_t)(row0 + quad * 4 + r) * 64 + 16 * j + l15] = __float2half(acc[j][r]);
}

// ---------------- aggregation v6: wave-pair neighbor split for 2x MLP ----------------
// Block = 16 nodes; waves (pair,half): node set = pair*8..+8, half h takes slots h,h+2,...
// Partials combined via LDS; half 0 does self-term + epilogue.
// mode 0: OUT = dinv * gelu_tanh( dinv*(Σ T[s] + T[d]) + b );  mode 1: no activation.

__device__ __forceinline__ void add8(float* acc, uintx4 v) {
    const __half2* h = (const __half2*)&v;
#pragma unroll
    for (int j = 0; j < 4; j++) {
        acc[2 * j]     += __low2float(h[j]);
        acc[2 * j + 1] += __high2float(h[j]);
    }
}

__global__ __launch_bounds__(256) void k_agg(const __half* __restrict__ T,
                                             const int* __restrict__ col,
                                             const int* __restrict__ deg,
                                             const float* __restrict__ dinv,
                                             const float* __restrict__ b,
                                             __half* __restrict__ OUT, int mode) {
    __shared__ int cols[AGG_NPB][MAX_DEG + 1];   // 4160 B
    __shared__ float part[2][8][65];             // pair, node, feat(+pad) = 4160 B
    int tid = threadIdx.x;
    int base = blockIdx.x * AGG_NPB;             // 3125 blocks exactly, no tail

    for (int idx = tid; idx < AGG_NPB * MAX_DEG; idx += 256) {
        int r = idx >> 6, j = idx & 63;
        cols[r][j] = __builtin_nontemporal_load(&col[(base + r) * MAX_DEG + j]);
    }
    __syncthreads();

    int lane = tid & 63, wv = tid >> 6;
    int pair = wv >> 1, half = wv & 1;
    int q = lane >> 3, t = lane & 7;             // q = node-in-8, t = 16B chunk
    int local = pair * 8 + q;
    int d = base + local;

    int dg = deg[d]; if (dg > MAX_DEG) dg = MAX_DEG;
    int cnt = (dg - half + 1) >> 1;              // # slots for this half (h, h+2, ...)

    float acc[8];
#pragma unroll
    for (int j = 0; j < 8; j++) acc[j] = 0.f;
    if (half == 0)
        add8(acc, *(const uintx4*)(T + (size_t)d * HID + t * 8));   // self term

    const int* cl = cols[local];
    int i = 0;
    for (; i + 8 <= cnt; i += 8) {
        uintx4 v[8];
#pragma unroll
        for (int u = 0; u < 8; u++)
            v[u] = *(const uintx4*)(T + (size_t)cl[2 * (i + u) + half] * HID + t * 8);
#pragma unroll
        for (int u = 0; u < 8; u++) add8(acc, v[u]);
    }
    for (; i + 2 <= cnt; i += 2) {
        uintx4 v0 = *(const uintx4*)(T + (size_t)cl[2 * i + half] * HID + t * 8);
        uintx4 v1 = *(const uintx4*)(T + (size_t)cl[2 * (i + 1) + half] * HID + t * 8);
        add8(acc, v0); add8(acc, v1);
    }
    if (i < cnt)
        add8(acc, *(const uintx4*)(T + (size_t)cl[2 * i + half] * HID + t * 8));

    if (half == 1) {
#pragma unroll
        for (int j = 0; j < 8; j++) part[pair][q][t * 8 + j] = acc[j];
    }
    __syncthreads();
    if (half == 0) {
#pragma unroll
        for (int j = 0; j < 8; j++) acc[j] += part[pair][q][t * 8 + j];

        float dv = dinv[d];
        float o[8];
#pragma unroll
        for (int j = 0; j < 8; j++) o[j] = acc[j] * dv;
        if (mode == 0) {
#pragma unroll
            for (int j = 0; j < 8; j++) {
                float v = o[j] + b[t * 8 + j];
                float u2 = 0.7978845608028654f * (v + 0.044715f * v * v * v);
                o[j] = 0.5f * v * (1.0f + tanhf(u2)) * dv;   // pre-scale for next layer
            }
        }
        __half2 hh[4];
#pragma unroll
        for (int j = 0; j < 4; j++) hh[j] = __floats2half2_rn(o[2 * j], o[2 * j + 1]);
        uintx4 st = *(uintx4*)hh;
        __builtin_nontemporal_store(st, (uintx4*)(OUT + (size_t)d * HID + t * 8));
    }
}

// ---------------- fused segmented mean-pool + final GEMM (batch is SORTED) ----------------

__global__ __launch_bounds__(256) void k_pool_out(const __half* __restrict__ A,
                                                  const int* __restrict__ batch,
                                                  const float* __restrict__ W3,
                                                  const float* __restrict__ b3,
                                                  float* __restrict__ out) {
    int g = blockIdx.x;
    int lo = 0, hi = N_NODES;
    while (lo < hi) { int m = (lo + hi) >> 1; if (batch[m] < g) lo = m + 1; else hi = m; }
    int lo2 = lo, hi2 = N_NODES;
    while (lo2 < hi2) { int m = (lo2 + hi2) >> 1; if (batch[m] < g + 1) lo2 = m + 1; else hi2 = m; }
    int start = lo, end = lo2;

    int lane = threadIdx.x & 63;
    int wave = threadIdx.x >> 6;
    float acc = 0.f;
    for (int n = start + wave; n < end; n += 4)
        acc += __half2float(A[(size_t)n * HID + lane]);

    __shared__ float part[4][HID];
    __shared__ float pooled[HID];
    part[wave][lane] = acc;
    __syncthreads();
    if (threadIdx.x < HID)
        pooled[threadIdx.x] = part[0][threadIdx.x] + part[1][threadIdx.x] +
                              part[2][threadIdx.x] + part[3][threadIdx.x];
    __syncthreads();

    if (threadIdx.x < OUT_DIM) {
        float cntf = (float)(end - start);
        float inv = 1.0f / fmaxf(cntf, 1.0f);
        float s = 0.f;
#pragma unroll
        for (int k = 0; k < HID; k++) s += pooled[k] * W3[k * OUT_DIM + threadIdx.x];
        out[g * OUT_DIM + threadIdx.x] = (s + cntf * b3[threadIdx.x]) * inv;
    }
}

// ---------------- launch ----------------

extern "C" void kernel_launch(void* const* d_in, const int* in_sizes, int n_in,
                              void* d_out, int out_size, void* d_ws, size_t ws_size,
                              hipStream_t stream) {
    const float* x     = (const float*)d_in[0];
    const int*   ei    = (const int*)d_in[1];
    const int*   batch = (const int*)d_in[2];
    const float* W1    = (const float*)d_in[4];
    const float* b1    = (const float*)d_in[5];
    const float* W2    = (const float*)d_in[6];
    const float* b2    = (const float*)d_in[7];
    const float* W3    = (const float*)d_in[8];
    const float* b3    = (const float*)d_in[9];
    float* out = (float*)d_out;

    const int* esrc = ei;
    const int* edst = ei + N_EDGES;

    // workspace layout
    int*    deg  = (int*)d_ws;                           // 50000 (zero; doubles as cursor)
    float*  dinv = (float*)(deg + N_NODES);              // 50000
    int*    col  = (int*)(dinv + N_NODES);               // 3.2M ints (12.8 MB)
    __half* t    = (__half*)(col + (size_t)N_NODES * MAX_DEG);   // 3.2M halves
    __half* p    = t + (size_t)N_NODES * HID;                    // 3.2M halves
    __half* Wt1  = p + (size_t)N_NODES * HID;                    // 8192 halves
    __half* Wt2  = Wt1 + IN_DIM * HID;                           // 4096 halves

    (void)hipMemsetAsync(deg, 0, (size_t)N_NODES * 4, stream);

    const int CHUNKS = (N_EDGES + EPB - 1) / EPB;        // 196
    k_build<<<CHUNKS * PARTS, 256, 0, stream>>>(esrc, edst, deg, col);
    k_prep<<<202, 256, 0, stream>>>(deg, dinv, W1, Wt1, W2, Wt2);

    const int GB = (N_NODES + 63) / 64;                  // 782 MFMA blocks
    const int AB = N_NODES / AGG_NPB;                    // 3125 agg blocks, exact

    // layer 1 (x-cvt + dinv pre-scale fused into MFMA A-load)
    k_mfma1<<<GB, 256, 0, stream>>>(x, dinv, Wt1, t);
    k_agg<<<AB, 256, 0, stream>>>(t, col, deg, dinv, b1, p, 0);
    // layer 2
    k_mfma2<<<GB, 256, 0, stream>>>(p, Wt2, t);
    k_agg<<<AB, 256, 0, stream>>>(t, col, deg, dinv, b2, p, 0);
    // layer 3 aggregate (width 64, pre-GEMM)
    k_agg<<<AB, 256, 0, stream>>>(p, col, deg, dinv, b3, t, 1);
    // fused mean-pool + 64->128 GEMM
    k_pool_out<<<N_GRAPHS, 256, 0, stream>>>(t, batch, W3, b3, out);
}